// Round 2
// baseline (3897.581 us; speedup 1.0000x reference)
//
#include <hip/hip_runtime.h>

// GuidedCnn: fused offset-conv (8ch -> 18ch, 3x3, pad 1) + deformable conv
// (pf 3ch sampled bilinearly at offsets, contracted with deform_w 3x3x9).
// B=8, H=W=384. All tensors float32 (per reference), math in f32.

#define Bn 8
#define Hn 384
#define Wn 384
#define HWn (Hn * Wn)

__global__ __launch_bounds__(256) void guided_cnn_fused(
    const float* __restrict__ pf, const float* __restrict__ cf,
    const float* __restrict__ mv, const float* __restrict__ ow,
    const float* __restrict__ ob, const float* __restrict__ dw,
    float* __restrict__ out)
{
    // offset_w transposed to [kpos=72][oc=18], rows padded to 20 floats (80 B,
    // 16B-aligned) so unrolled reads can merge into ds_read_b128.
    __shared__ float wlds[72 * 20];
    __shared__ float dwlds[81];   // [o=3][i=3][k=9]
    __shared__ float blds[18];

    const int tid = threadIdx.x;
    for (int i = tid; i < 1296; i += 256) {
        int oc = i / 72;
        int r  = i - oc * 72;          // r = ic*9 + ky*3 + kx
        wlds[r * 20 + oc] = ow[i];
    }
    if (tid < 81) dwlds[tid] = dw[tid];
    if (tid < 18) blds[tid]  = ob[tid];
    __syncthreads();

    const int idx = blockIdx.x * 256 + tid;
    if (idx >= Bn * HWn) return;
    const int x = idx % Wn;
    const int t = idx / Wn;
    const int y = t % Hn;
    const int b = t / Hn;

    // ---- Stage 1: 18 offset-conv outputs for this pixel ----
    float offs[18];
#pragma unroll
    for (int oc = 0; oc < 18; ++oc) offs[oc] = blds[oc];

#pragma unroll
    for (int ic = 0; ic < 8; ++ic) {
        const float* plane;
        if (ic < 3)      plane = pf + ((size_t)b * 3 + ic) * HWn;
        else if (ic < 6) plane = cf + ((size_t)b * 3 + (ic - 3)) * HWn;
        else             plane = mv + ((size_t)b * 2 + (ic - 6)) * HWn;
#pragma unroll
        for (int ky = 0; ky < 3; ++ky) {
            const int yy = y + ky - 1;
            const bool yv = ((unsigned)yy < (unsigned)Hn);
#pragma unroll
            for (int kx = 0; kx < 3; ++kx) {
                const int xx = x + kx - 1;
                const bool v = yv && ((unsigned)xx < (unsigned)Wn);
                const float p = v ? plane[yy * Wn + xx] : 0.f;
                const float* wr = &wlds[(ic * 9 + ky * 3 + kx) * 20];
#pragma unroll
                for (int oc = 0; oc < 18; ++oc)
                    offs[oc] = fmaf(p, wr[oc], offs[oc]);
            }
        }
    }

    // ---- Stage 2: deformable conv on pf ----
    const float* p0 = pf + (size_t)b * 3 * HWn;
    float acc[3] = {0.f, 0.f, 0.f};

#pragma unroll
    for (int k = 0; k < 9; ++k) {
        const int ky = k / 3;
        const int kx = k - ky * 3;
        const float py = offs[2 * k]     + (float)(y + ky - 1);
        const float px = offs[2 * k + 1] + (float)(x + kx - 1);
        const float y0f = floorf(py);
        const float x0f = floorf(px);
        const float wy = py - y0f;
        const float wx = px - x0f;
        const int y0 = (int)y0f, x0 = (int)x0f;
        const int y1 = y0 + 1,  x1 = x0 + 1;
        const bool vy0 = ((unsigned)y0 < (unsigned)Hn);
        const bool vy1 = ((unsigned)y1 < (unsigned)Hn);
        const bool vx0 = ((unsigned)x0 < (unsigned)Wn);
        const bool vx1 = ((unsigned)x1 < (unsigned)Wn);
        const int y0c = min(max(y0, 0), Hn - 1);
        const int y1c = min(max(y1, 0), Hn - 1);
        const int x0c = min(max(x0, 0), Wn - 1);
        const int x1c = min(max(x1, 0), Wn - 1);
        const float w00 = (1.f - wy) * (1.f - wx);
        const float w01 = (1.f - wy) * wx;
        const float w10 = wy * (1.f - wx);
        const float w11 = wy * wx;
        const int i00 = y0c * Wn + x0c;
        const int i01 = y0c * Wn + x1c;
        const int i10 = y1c * Wn + x0c;
        const int i11 = y1c * Wn + x1c;
#pragma unroll
        for (int i = 0; i < 3; ++i) {
            const float* pl = p0 + (size_t)i * HWn;
            const float v00 = (vy0 && vx0) ? pl[i00] : 0.f;
            const float v01 = (vy0 && vx1) ? pl[i01] : 0.f;
            const float v10 = (vy1 && vx0) ? pl[i10] : 0.f;
            const float v11 = (vy1 && vx1) ? pl[i11] : 0.f;
            const float s = w00 * v00 + w01 * v01 + w10 * v10 + w11 * v11;
#pragma unroll
            for (int o = 0; o < 3; ++o)
                acc[o] = fmaf(dwlds[o * 27 + i * 9 + k], s, acc[o]);
        }
    }

#pragma unroll
    for (int o = 0; o < 3; ++o) {
        out[(((size_t)b * 3 + o) * Hn + y) * Wn + x] = acc[o];
    }
}

extern "C" void kernel_launch(void* const* d_in, const int* in_sizes, int n_in,
                              void* d_out, int out_size, void* d_ws, size_t ws_size,
                              hipStream_t stream) {
    const float* pf = (const float*)d_in[0];
    const float* cf = (const float*)d_in[1];
    const float* mv = (const float*)d_in[2];
    const float* ow = (const float*)d_in[3];
    const float* ob = (const float*)d_in[4];
    const float* dw = (const float*)d_in[5];
    float* out = (float*)d_out;

    const int total  = Bn * HWn;            // 1,179,648 pixels
    const int blocks = (total + 255) / 256; // 4608
    guided_cnn_fused<<<blocks, 256, 0, stream>>>(pf, cf, mv, ow, ob, dw, out);
}

// Round 3
// 376.080 us; speedup vs baseline: 10.3637x; 10.3637x over previous
//
#include <hip/hip_runtime.h>

// GuidedCnn: fused offset-conv (8ch -> 18ch, 3x3, pad 1) + deformable conv
// (pf 3ch sampled bilinearly at offsets, contracted with deform_w 3x3x9).
// B=8, H=W=384. All tensors float32, math in f32.
//
// R2 fix: stage the 18x18x8 input halo tile in LDS (conv reads become
// ds_read, no batched global loads) + __launch_bounds__(256,4) to cap
// VGPRs at 128. R1 version spilled (VGPR=256, 8.4 GB scratch traffic).

#define Bn 8
#define Hn 384
#define Wn 384
#define HWn (Hn * Wn)
#define TILE 16
#define HT 18          // halo tile extent
#define ST 20          // padded LDS row stride
#define CH_STRIDE (HT * ST)   // 360 floats per channel plane

__global__ __launch_bounds__(256, 4) void guided_cnn_fused(
    const float* __restrict__ pf, const float* __restrict__ cf,
    const float* __restrict__ mv, const float* __restrict__ ow,
    const float* __restrict__ ob, const float* __restrict__ dw,
    float* __restrict__ out)
{
    __shared__ float tile[8 * CH_STRIDE];   // 2880 floats, 11.5 KB
    __shared__ float wlds[72 * ST];         // [kpos=72][oc=18 pad 20], 5.8 KB
    __shared__ float dwlds[81];             // [o=3][i=3][k=9]
    __shared__ float blds[18];

    const int tid = threadIdx.x;
    const int b = blockIdx.z;
    const int tileY0 = blockIdx.y * TILE;
    const int tileX0 = blockIdx.x * TILE;

    // --- stage offset_w transposed [kpos][oc], bias, deform_w ---
    for (int i = tid; i < 1296; i += 256) {
        int oc = i / 72;
        int r  = i - oc * 72;          // r = ic*9 + ky*3 + kx
        wlds[r * ST + oc] = ow[i];
    }
    if (tid < 81) dwlds[tid] = dw[tid];
    if (tid < 18) blds[tid]  = ob[tid];

    // --- stage 18x18 halo x 8 channels ---
    for (int i = tid; i < 8 * HT * HT; i += 256) {
        int c   = i / (HT * HT);
        int r   = i - c * (HT * HT);
        int row = r / HT;
        int col = r - row * HT;
        int gy  = tileY0 + row - 1;
        int gx  = tileX0 + col - 1;
        const float* plane;
        if (c < 3)      plane = pf + ((size_t)b * 3 + c) * HWn;
        else if (c < 6) plane = cf + ((size_t)b * 3 + (c - 3)) * HWn;
        else            plane = mv + ((size_t)b * 2 + (c - 6)) * HWn;
        const bool v = ((unsigned)gy < (unsigned)Hn) && ((unsigned)gx < (unsigned)Wn);
        tile[c * CH_STRIDE + row * ST + col] = v ? plane[gy * Wn + gx] : 0.f;
    }
    __syncthreads();

    const int tx = tid & (TILE - 1);
    const int ty = tid >> 4;
    const int x = tileX0 + tx;
    const int y = tileY0 + ty;

    // ---- Stage 1: 18 offset-conv outputs for this pixel (from LDS) ----
    float offs[18];
#pragma unroll
    for (int oc = 0; oc < 18; ++oc) offs[oc] = blds[oc];

    for (int c = 0; c < 8; ++c) {
        const float* tp = &tile[c * CH_STRIDE + ty * ST + tx];
        const float* wp = &wlds[c * 9 * ST];
#pragma unroll
        for (int ky = 0; ky < 3; ++ky) {
#pragma unroll
            for (int kx = 0; kx < 3; ++kx) {
                const float p = tp[ky * ST + kx];
                const float* wr = wp + (ky * 3 + kx) * ST;
#pragma unroll
                for (int oc = 0; oc < 18; ++oc)
                    offs[oc] = fmaf(p, wr[oc], offs[oc]);
            }
        }
    }

    // ---- Stage 2: deformable conv on pf (global gathers, L1/L2-local) ----
    const float* p0 = pf + (size_t)b * 3 * HWn;
    float acc[3] = {0.f, 0.f, 0.f};

#pragma unroll
    for (int k = 0; k < 9; ++k) {
        const int ky = k / 3;
        const int kx = k - ky * 3;
        const float py = offs[2 * k]     + (float)(y + ky - 1);
        const float px = offs[2 * k + 1] + (float)(x + kx - 1);
        const float y0f = floorf(py);
        const float x0f = floorf(px);
        const float wy = py - y0f;
        const float wx = px - x0f;
        const int y0 = (int)y0f, x0 = (int)x0f;
        const int y1 = y0 + 1,  x1 = x0 + 1;
        const bool vy0 = ((unsigned)y0 < (unsigned)Hn);
        const bool vy1 = ((unsigned)y1 < (unsigned)Hn);
        const bool vx0 = ((unsigned)x0 < (unsigned)Wn);
        const bool vx1 = ((unsigned)x1 < (unsigned)Wn);
        const int y0c = min(max(y0, 0), Hn - 1);
        const int y1c = min(max(y1, 0), Hn - 1);
        const int x0c = min(max(x0, 0), Wn - 1);
        const int x1c = min(max(x1, 0), Wn - 1);
        const float w00 = (1.f - wy) * (1.f - wx);
        const float w01 = (1.f - wy) * wx;
        const float w10 = wy * (1.f - wx);
        const float w11 = wy * wx;
        const int i00 = y0c * Wn + x0c;
        const int i01 = y0c * Wn + x1c;
        const int i10 = y1c * Wn + x0c;
        const int i11 = y1c * Wn + x1c;
#pragma unroll
        for (int i = 0; i < 3; ++i) {
            const float* pl = p0 + (size_t)i * HWn;
            const float v00 = (vy0 && vx0) ? pl[i00] : 0.f;
            const float v01 = (vy0 && vx1) ? pl[i01] : 0.f;
            const float v10 = (vy1 && vx0) ? pl[i10] : 0.f;
            const float v11 = (vy1 && vx1) ? pl[i11] : 0.f;
            const float s = w00 * v00 + w01 * v01 + w10 * v10 + w11 * v11;
#pragma unroll
            for (int o = 0; o < 3; ++o)
                acc[o] = fmaf(dwlds[o * 27 + i * 9 + k], s, acc[o]);
        }
    }

#pragma unroll
    for (int o = 0; o < 3; ++o) {
        out[(((size_t)b * 3 + o) * Hn + y) * Wn + x] = acc[o];
    }
}

extern "C" void kernel_launch(void* const* d_in, const int* in_sizes, int n_in,
                              void* d_out, int out_size, void* d_ws, size_t ws_size,
                              hipStream_t stream) {
    const float* pf = (const float*)d_in[0];
    const float* cf = (const float*)d_in[1];
    const float* mv = (const float*)d_in[2];
    const float* ob = (const float*)d_in[4];
    const float* ow = (const float*)d_in[3];
    const float* dw = (const float*)d_in[5];
    float* out = (float*)d_out;

    dim3 grid(Wn / TILE, Hn / TILE, Bn);   // 24 x 24 x 8
    guided_cnn_fused<<<grid, 256, 0, stream>>>(pf, cf, mv, ow, ob, dw, out);
}

// Round 4
// 271.752 us; speedup vs baseline: 14.3424x; 1.3839x over previous
//
#include <hip/hip_runtime.h>

// GuidedCnn: fused offset-conv (8ch -> 18ch, 3x3, pad 1) + deformable conv
// (pf 3ch sampled bilinearly at offsets, contracted with deform_w 3x3x9).
// B=8, H=W=384. All tensors float32, math in f32.
//
// R4: (1) conv weights read via wave-uniform global loads -> s_load into
// SGPRs (frees LDS unit; v_fma takes SGPR operand). (2) pf staged with
// halo-8 32x32 LDS tile so stage-2 bilinear gathers are ds_read_b32, with
// a guarded global fallback for out-of-tile samples. (3) 5 blocks/CU.

#define Bn 8
#define Hn 384
#define Wn 384
#define HWn (Hn * Wn)
#define TILE 16
#define PH 8                 // sampling halo
#define PT 32                // TILE + 2*PH
#define PS 33                // padded row stride (bank-conflict break)
#define PPLANE (PT * PS)     // 1056 floats per pf plane
#define HT 18                // conv halo tile extent for cf/mv
#define ST 20                // padded stride
#define CPLANE (HT * ST)     // 360 floats per cf/mv plane

__global__ __launch_bounds__(256, 5) void guided_cnn_fused(
    const float* __restrict__ pf, const float* __restrict__ cf,
    const float* __restrict__ mv, const float* __restrict__ ow,
    const float* __restrict__ ob, const float* __restrict__ dw,
    float* __restrict__ out)
{
    __shared__ float ptile[3 * PPLANE];   // 12672 B: pf with halo 8
    __shared__ float ctile[5 * CPLANE];   // 7200 B: cf+mv with halo 1

    const int tid = threadIdx.x;
    const int b = blockIdx.z;
    const int tileY0 = blockIdx.y * TILE;
    const int tileX0 = blockIdx.x * TILE;
    const int oy = tileY0 - PH;
    const int ox = tileX0 - PH;

    // --- stage pf 3ch, 32x32 halo-8 (coalesced: 32 lanes = one row) ---
    for (int i = tid; i < 3 * PT * PT; i += 256) {
        const int c   = i >> 10;          // /1024
        const int rem = i & 1023;
        const int row = rem >> 5;
        const int col = rem & 31;
        const int gy = oy + row;
        const int gx = ox + col;
        const bool v = ((unsigned)gy < (unsigned)Hn) && ((unsigned)gx < (unsigned)Wn);
        ptile[c * PPLANE + row * PS + col] =
            v ? pf[((size_t)b * 3 + c) * HWn + gy * Wn + gx] : 0.f;
    }
    // --- stage cf (3ch) + mv (2ch), 18x18 halo-1 ---
    for (int i = tid; i < 5 * HT * HT; i += 256) {
        const int c   = i / (HT * HT);
        const int rem = i - c * (HT * HT);
        const int row = rem / HT;
        const int col = rem - row * HT;
        const int gy = tileY0 + row - 1;
        const int gx = tileX0 + col - 1;
        const float* plane = (c < 3) ? cf + ((size_t)b * 3 + c) * HWn
                                     : mv + ((size_t)b * 2 + (c - 3)) * HWn;
        const bool v = ((unsigned)gy < (unsigned)Hn) && ((unsigned)gx < (unsigned)Wn);
        ctile[c * CPLANE + row * ST + col] = v ? plane[gy * Wn + gx] : 0.f;
    }
    __syncthreads();

    const int tx = tid & (TILE - 1);
    const int ty = tid >> 4;
    const int x = tileX0 + tx;
    const int y = tileY0 + ty;

    // ---- Stage 1: offset conv. Weights via uniform (scalar) loads. ----
    float offs[18];
#pragma unroll
    for (int oc = 0; oc < 18; ++oc) offs[oc] = ob[oc];

#pragma unroll
    for (int ic = 0; ic < 8; ++ic) {
        float p[9];
        if (ic < 3) {
            const float* tp = &ptile[ic * PPLANE + (PH - 1 + ty) * PS + (PH - 1 + tx)];
#pragma unroll
            for (int t = 0; t < 9; ++t) p[t] = tp[(t / 3) * PS + (t % 3)];
        } else {
            const float* tp = &ctile[(ic - 3) * CPLANE + ty * ST + tx];
#pragma unroll
            for (int t = 0; t < 9; ++t) p[t] = tp[(t / 3) * ST + (t % 3)];
        }
        const float* wp = ow + ic * 9;   // + oc*72 + t, uniform -> s_load
#pragma unroll
        for (int oc = 0; oc < 18; ++oc) {
            const float* wr = wp + oc * 72;
#pragma unroll
            for (int t = 0; t < 9; ++t)
                offs[oc] = fmaf(p[t], wr[t], offs[oc]);
        }
    }

    // ---- Stage 2: deformable conv, bilinear sampling from LDS tile ----
    const float* p0 = pf + (size_t)b * 3 * HWn;
    float acc[3] = {0.f, 0.f, 0.f};

#pragma unroll
    for (int k = 0; k < 9; ++k) {
        const int ky = k / 3;
        const int kx = k - ky * 3;
        const float py = offs[2 * k]     + (float)(y + ky - 1);
        const float px = offs[2 * k + 1] + (float)(x + kx - 1);
        const float y0f = floorf(py);
        const float x0f = floorf(px);
        const float wy = py - y0f;
        const float wx = px - x0f;
        const int y0 = (int)y0f, x0 = (int)x0f;
        const int y1 = y0 + 1,  x1 = x0 + 1;
        const bool vy0 = ((unsigned)y0 < (unsigned)Hn);
        const bool vy1 = ((unsigned)y1 < (unsigned)Hn);
        const bool vx0 = ((unsigned)x0 < (unsigned)Wn);
        const bool vx1 = ((unsigned)x1 < (unsigned)Wn);
        const int y0c = min(max(y0, 0), Hn - 1);
        const int y1c = min(max(y1, 0), Hn - 1);
        const int x0c = min(max(x0, 0), Wn - 1);
        const int x1c = min(max(x1, 0), Wn - 1);
        const float w00 = (1.f - wy) * (1.f - wx);
        const float w01 = (1.f - wy) * wx;
        const float w10 = wy * (1.f - wx);
        const float w11 = wy * wx;

        const int ty0 = y0c - oy, tx0 = x0c - ox;
        const int ty1 = y1c - oy, tx1 = x1c - ox;
        const bool inT = ((unsigned)ty0 < (unsigned)PT) && ((unsigned)ty1 < (unsigned)PT) &&
                         ((unsigned)tx0 < (unsigned)PT) && ((unsigned)tx1 < (unsigned)PT);

        if (inT) {
            const int i00 = ty0 * PS + tx0;
            const int i01 = ty0 * PS + tx1;
            const int i10 = ty1 * PS + tx0;
            const int i11 = ty1 * PS + tx1;
#pragma unroll
            for (int i = 0; i < 3; ++i) {
                const float* base = &ptile[i * PPLANE];
                const float v00 = (vy0 && vx0) ? base[i00] : 0.f;
                const float v01 = (vy0 && vx1) ? base[i01] : 0.f;
                const float v10 = (vy1 && vx0) ? base[i10] : 0.f;
                const float v11 = (vy1 && vx1) ? base[i11] : 0.f;
                const float s = w00 * v00 + w01 * v01 + w10 * v10 + w11 * v11;
#pragma unroll
                for (int o = 0; o < 3; ++o)
                    acc[o] = fmaf(dw[o * 27 + i * 9 + k], s, acc[o]);
            }
        } else {
            const int i00 = y0c * Wn + x0c;
            const int i01 = y0c * Wn + x1c;
            const int i10 = y1c * Wn + x0c;
            const int i11 = y1c * Wn + x1c;
#pragma unroll
            for (int i = 0; i < 3; ++i) {
                const float* pl = p0 + (size_t)i * HWn;
                const float v00 = (vy0 && vx0) ? pl[i00] : 0.f;
                const float v01 = (vy0 && vx1) ? pl[i01] : 0.f;
                const float v10 = (vy1 && vx0) ? pl[i10] : 0.f;
                const float v11 = (vy1 && vx1) ? pl[i11] : 0.f;
                const float s = w00 * v00 + w01 * v01 + w10 * v10 + w11 * v11;
#pragma unroll
                for (int o = 0; o < 3; ++o)
                    acc[o] = fmaf(dw[o * 27 + i * 9 + k], s, acc[o]);
            }
        }
    }

#pragma unroll
    for (int o = 0; o < 3; ++o) {
        out[(((size_t)b * 3 + o) * Hn + y) * Wn + x] = acc[o];
    }
}

extern "C" void kernel_launch(void* const* d_in, const int* in_sizes, int n_in,
                              void* d_out, int out_size, void* d_ws, size_t ws_size,
                              hipStream_t stream) {
    const float* pf = (const float*)d_in[0];
    const float* cf = (const float*)d_in[1];
    const float* mv = (const float*)d_in[2];
    const float* ow = (const float*)d_in[3];
    const float* ob = (const float*)d_in[4];
    const float* dw = (const float*)d_in[5];
    float* out = (float*)d_out;

    dim3 grid(Wn / TILE, Hn / TILE, Bn);   // 24 x 24 x 8
    guided_cnn_fused<<<grid, 256, 0, stream>>>(pf, cf, mv, ow, ob, dw, out);
}

// Round 5
// 167.800 us; speedup vs baseline: 23.2275x; 1.6195x over previous
//
#include <hip/hip_runtime.h>

// GuidedCnn: fused offset-conv (8ch -> 18ch, 3x3) + deformable conv.
// R5: offset conv via bf16 MFMA (16x16x32). Weights live in 32 VGPRs as
// B-fragments (kills the R3/R4 weight-streaming stall: 1296 wts/pixel can't
// be register-resident in a VALU formulation). A-frags = im2col from LDS.
// D redistributed pixel-major via LDS; stage-2 bilinear kept from R4.

#define Bn 8
#define Hn 384
#define Wn 384
#define HWn (Hn * Wn)
#define TILE 16
#define PH 8
#define PT 32                  // sampling tile extent (halo 8)
#define PS 33                  // padded stride
#define PPLANE (PT * PS)       // 1056
#define CROWS 18               // conv tile rows (halo 1)
#define CSTR 33                // conv tile stride (match PS: uniform addressing)
#define CPL (CROWS * CSTR)     // 594

// LDS float-offset map
#define OFF_PTILE 0
#define SZ_PTILE (3 * PPLANE)            // 3168
#define OFF_T8   SZ_PTILE                // conv tile (stage 1) ...
#define SZ_T8    (8 * CPL)               // 4752
#define SZ_OFFB  (256 * 19)              // 4864 (union over T8, stage 2)
#define OFF_BW   (OFF_T8 + SZ_OFFB)      // 8032
#define SZ_BW    1280                    // 128x20 ushort = 5120 B
#define SMEM_FLOATS (OFF_BW + SZ_BW)     // 9312 floats = 37,248 B

typedef float f32x4 __attribute__((ext_vector_type(4)));
typedef short s16x8 __attribute__((ext_vector_type(8)));

__device__ inline unsigned pack_bf16(float lo, float hi) {
    // truncation-to-bf16 pack: lo -> bits[15:0], hi -> bits[31:16]
    return (__float_as_uint(hi) & 0xffff0000u) | (__float_as_uint(lo) >> 16);
}

__global__ __launch_bounds__(256, 4) void guided_cnn_fused(
    const float* __restrict__ pf, const float* __restrict__ cf,
    const float* __restrict__ mv, const float* __restrict__ ow,
    const float* __restrict__ ob, const float* __restrict__ dw,
    float* __restrict__ out)
{
    __shared__ float smem[SMEM_FLOATS];

    const int tid = threadIdx.x;
    const int b = blockIdx.z;
    const int tileY0 = blockIdx.y * TILE;
    const int tileX0 = blockIdx.x * TILE;
    const int oy = tileY0 - PH;
    const int ox = tileX0 - PH;

    float* ptile = smem + OFF_PTILE;
    float* t8    = smem + OFF_T8;

    // ---- phase 0: zero bw; stage ptile (pf halo-8) + t8 (8ch conv halo-1) ----
    {
        unsigned* bz = (unsigned*)(smem + OFF_BW);
        for (int i = tid; i < SZ_BW; i += 256) bz[i] = 0u;
    }
    for (int i = tid; i < 3 * PT * PT; i += 256) {
        const int c   = i >> 10;
        const int rem = i & 1023;
        const int row = rem >> 5;
        const int col = rem & 31;
        const int gy = oy + row, gx = ox + col;
        const bool v = ((unsigned)gy < (unsigned)Hn) && ((unsigned)gx < (unsigned)Wn);
        ptile[c * PPLANE + row * PS + col] =
            v ? pf[((size_t)b * 3 + c) * HWn + gy * Wn + gx] : 0.f;
    }
    for (int i = tid; i < 8 * 18 * 18; i += 256) {
        const int c   = i / 324;
        const int rem = i - c * 324;
        const int row = rem / 18;
        const int col = rem - row * 18;
        const int gy = tileY0 + row - 1, gx = tileX0 + col - 1;
        const float* plane;
        if (c < 3)      plane = pf + ((size_t)b * 3 + c) * HWn;
        else if (c < 6) plane = cf + ((size_t)b * 3 + (c - 3)) * HWn;
        else            plane = mv + ((size_t)b * 2 + (c - 6)) * HWn;
        const bool v = ((unsigned)gy < (unsigned)Hn) && ((unsigned)gx < (unsigned)Wn);
        t8[c * CPL + row * CSTR + col] = v ? plane[gy * Wn + gx] : 0.f;
    }
    __syncthreads();

    // ---- phase 1: fill bw[k=c*16+t][oc] (bf16 RNE), k-order matches A-frags ----
    {
        unsigned short* bw = (unsigned short*)(smem + OFF_BW);
        for (int i = tid; i < 1296; i += 256) {
            const int oc = i / 72;
            const int r  = i - oc * 72;      // c*9 + t
            const int c  = r / 9;
            const int t  = r - c * 9;
            unsigned u = __float_as_uint(ow[i]);
            u += 0x7fffu + ((u >> 16) & 1u);           // RNE
            bw[(c * 16 + t) * 20 + oc] = (unsigned short)(u >> 16);
        }
    }
    __syncthreads();

    // ---- phase 2: MFMA GEMM  [256 x 128] @ [128 x 32] ----
    const int lane  = tid & 63;
    const int wv    = tid >> 6;
    const int am    = lane & 15;       // A row in m-tile (= pixel tx); also B col
    const int g     = lane >> 4;       // quad 0..3
    const bool hiK  = (g & 1);         // quad holds taps 8..15 of its channel
    const int chalf = lane >> 5;       // channel parity within K-step

    // B-fragments: lane holds B[k = 32s+8g+j][n = nt*16+am]
    s16x8 bfrag[4][2];
    {
        const unsigned short* bw = (const unsigned short*)(smem + OFF_BW);
        const bool ok1 = (am < 2);
        const int nc1  = 16 + (am < 2 ? am : 3);   // clamped, in-range col
#pragma unroll
        for (int s = 0; s < 4; ++s) {
            const int kbase = 32 * s + 8 * g;
#pragma unroll
            for (int nt = 0; nt < 2; ++nt) {
                const int nc = nt ? nc1 : am;
                s16x8 f;
#pragma unroll
                for (int j = 0; j < 8; ++j) {
                    unsigned short v = bw[(kbase + j) * 20 + nc];
                    f[j] = (nt == 0 || ok1) ? (short)v : (short)0;
                }
                bfrag[s][nt] = f;
            }
        }
    }

    f32x4 acc[4][2];
#pragma unroll
    for (int mt = 0; mt < 4; ++mt)
#pragma unroll
        for (int nt = 0; nt < 2; ++nt)
            acc[mt][nt] = (f32x4){0.f, 0.f, 0.f, 0.f};

#pragma unroll
    for (int mt = 0; mt < 4; ++mt) {
        const int mrow = wv * 4 + mt;            // pixel ty
#pragma unroll
        for (int s = 0; s < 4; ++s) {
            const int c = 2 * s + chalf;
            const float* ap = t8 + c * CPL + mrow * CSTR + am;
            const float t0 = ap[0],        t1 = ap[1],        t2 = ap[2];
            const float t3 = ap[CSTR],     t4 = ap[CSTR + 1], t5 = ap[CSTR + 2];
            const float t6 = ap[2*CSTR],   t7 = ap[2*CSTR+1], t8v = ap[2*CSTR+2];
            union { unsigned u[4]; s16x8 v; } A;
            A.u[0] = hiK ? (__float_as_uint(t8v) >> 16) : pack_bf16(t0, t1);
            A.u[1] = hiK ? 0u : pack_bf16(t2, t3);
            A.u[2] = hiK ? 0u : pack_bf16(t4, t5);
            A.u[3] = hiK ? 0u : pack_bf16(t6, t7);
            acc[mt][0] = __builtin_amdgcn_mfma_f32_16x16x32_bf16(A.v, bfrag[s][0], acc[mt][0], 0, 0, 0);
            acc[mt][1] = __builtin_amdgcn_mfma_f32_16x16x32_bf16(A.v, bfrag[s][1], acc[mt][1], 0, 0, 0);
        }
    }
    __syncthreads();   // all A-reads of t8 done; bw dead

    // ---- phase 3: redistribute D -> offbuf[pixel][oc] (stride 19) ----
    float* offb = smem + OFF_T8;   // union over t8
#pragma unroll
    for (int mt = 0; mt < 4; ++mt) {
        const int prow = wv * 4 + mt;            // ty
#pragma unroll
        for (int r = 0; r < 4; ++r) {
            const int px  = g * 4 + r;           // D row = tx
            const int pix = prow * 16 + px;
            offb[pix * 19 + am] = acc[mt][0][r];
            if (am < 2) offb[pix * 19 + 16 + am] = acc[mt][1][r];
        }
    }
    __syncthreads();

    // ---- phase 4: per-pixel offsets + stage-2 deformable conv ----
    const int tx = tid & 15;
    const int ty = tid >> 4;
    const int x = tileX0 + tx;
    const int y = tileY0 + ty;

    float offs[18];
#pragma unroll
    for (int j = 0; j < 18; ++j) offs[j] = offb[tid * 19 + j] + ob[j];

    const float* p0 = pf + (size_t)b * 3 * HWn;
    float acc2[3] = {0.f, 0.f, 0.f};

#pragma unroll
    for (int k = 0; k < 9; ++k) {
        const int ky = k / 3;
        const int kx = k - ky * 3;
        const float py = offs[2 * k]     + (float)(y + ky - 1);
        const float px = offs[2 * k + 1] + (float)(x + kx - 1);
        const float y0f = floorf(py);
        const float x0f = floorf(px);
        const float wy = py - y0f;
        const float wx = px - x0f;
        const int y0 = (int)y0f, x0 = (int)x0f;
        const int y1 = y0 + 1,  x1 = x0 + 1;
        const bool vy0 = ((unsigned)y0 < (unsigned)Hn);
        const bool vy1 = ((unsigned)y1 < (unsigned)Hn);
        const bool vx0 = ((unsigned)x0 < (unsigned)Wn);
        const bool vx1 = ((unsigned)x1 < (unsigned)Wn);
        const int y0c = min(max(y0, 0), Hn - 1);
        const int y1c = min(max(y1, 0), Hn - 1);
        const int x0c = min(max(x0, 0), Wn - 1);
        const int x1c = min(max(x1, 0), Wn - 1);
        const float w00 = (1.f - wy) * (1.f - wx);
        const float w01 = (1.f - wy) * wx;
        const float w10 = wy * (1.f - wx);
        const float w11 = wy * wx;

        const int ty0 = y0c - oy, tx0 = x0c - ox;
        const int ty1 = y1c - oy, tx1 = x1c - ox;
        const bool inT = ((unsigned)ty0 < (unsigned)PT) && ((unsigned)ty1 < (unsigned)PT) &&
                         ((unsigned)tx0 < (unsigned)PT) && ((unsigned)tx1 < (unsigned)PT);

        if (inT) {
            const int i00 = ty0 * PS + tx0;
            const int i01 = ty0 * PS + tx1;
            const int i10 = ty1 * PS + tx0;
            const int i11 = ty1 * PS + tx1;
#pragma unroll
            for (int i = 0; i < 3; ++i) {
                const float* base = &ptile[i * PPLANE];
                const float v00 = (vy0 && vx0) ? base[i00] : 0.f;
                const float v01 = (vy0 && vx1) ? base[i01] : 0.f;
                const float v10 = (vy1 && vx0) ? base[i10] : 0.f;
                const float v11 = (vy1 && vx1) ? base[i11] : 0.f;
                const float s = w00 * v00 + w01 * v01 + w10 * v10 + w11 * v11;
#pragma unroll
                for (int o = 0; o < 3; ++o)
                    acc2[o] = fmaf(dw[o * 27 + i * 9 + k], s, acc2[o]);
            }
        } else {
            const int i00 = y0c * Wn + x0c;
            const int i01 = y0c * Wn + x1c;
            const int i10 = y1c * Wn + x0c;
            const int i11 = y1c * Wn + x1c;
#pragma unroll
            for (int i = 0; i < 3; ++i) {
                const float* pl = p0 + (size_t)i * HWn;
                const float v00 = (vy0 && vx0) ? pl[i00] : 0.f;
                const float v01 = (vy0 && vx1) ? pl[i01] : 0.f;
                const float v10 = (vy1 && vx0) ? pl[i10] : 0.f;
                const float v11 = (vy1 && vx1) ? pl[i11] : 0.f;
                const float s = w00 * v00 + w01 * v01 + w10 * v10 + w11 * v11;
#pragma unroll
                for (int o = 0; o < 3; ++o)
                    acc2[o] = fmaf(dw[o * 27 + i * 9 + k], s, acc2[o]);
            }
        }
    }

#pragma unroll
    for (int o = 0; o < 3; ++o) {
        out[(((size_t)b * 3 + o) * Hn + y) * Wn + x] = acc2[o];
    }
}

extern "C" void kernel_launch(void* const* d_in, const int* in_sizes, int n_in,
                              void* d_out, int out_size, void* d_ws, size_t ws_size,
                              hipStream_t stream) {
    const float* pf = (const float*)d_in[0];
    const float* cf = (const float*)d_in[1];
    const float* mv = (const float*)d_in[2];
    const float* ow = (const float*)d_in[3];
    const float* ob = (const float*)d_in[4];
    const float* dw = (const float*)d_in[5];
    float* out = (float*)d_out;

    dim3 grid(Wn / TILE, Hn / TILE, Bn);   // 24 x 24 x 8
    guided_cnn_fused<<<grid, 256, 0, stream>>>(pf, cf, mv, ow, ob, dw, out);
}